// Round 11
// baseline (1339.611 us; speedup 1.0000x reference)
//
#include <hip/hip_runtime.h>

typedef _Float16 half_t;
typedef _Float16 half4 __attribute__((ext_vector_type(4)));
typedef _Float16 half8 __attribute__((ext_vector_type(8)));
typedef float floatx4 __attribute__((ext_vector_type(4)));
typedef unsigned long long ull_t;

typedef __attribute__((address_space(1))) const void gv1_t;
typedef __attribute__((address_space(3))) void lv3_t;

#define SEQ 256
#define BATCH 64
#define EMB 256
#define HID 512
#define NOUT 18
#define M_TOT (SEQ*BATCH)   // 16384

// rnn_layer geometry (round 11 = round 9/10 layout, unchanged)
#define KK_REG 12            // K-tiles (of 32) in registers: k < 384
#define K_REG  (KK_REG*32)   // 384
#define WTILE_BYTES (4*HID*64)        // wlds [4 kt][512 j][64 B] = 131072
#define HBUF_BYTES  (16*16*64)        // one h buffer [16 kk][16 b][64 B] = 16384
#define LDS_BYTES (WTILE_BYTES + 2*HBUF_BYTES)  // 163840 = full 160 KiB

// ---------------- ws layout (bytes) ----------------
#define O_WHH0_16 0u          // 2*512*512 half = 1048576
#define O_WHH1_16 1048576u    // 1048576
#define O_EMFC16  2097152u    // 65536 half = 131072
#define O_WIH0    2228224u    // 1024*256 half = 524288
#define O_WIH1    2752512u    // 1024*1024 half = 2097152
#define O_FC16    4849664u    // 18*1024 half = 36864
#define O_PE      4886528u    // post_emb 16384*256 half = 8388608
#define O_XP      13275136u   // xp 16384*1024 half = 33554432 (shared by layer0/layer1)
#define O_OUT     46829568u   // 16384*1024 half (out0/out1 aliased; stream-ordered safe)
// total 80384000 bytes

// ---------------- fused fp32 -> fp16 convert: 6 segments, one launch ----------------
struct CvtJobs { const float* s[6]; half_t* d[6]; int n8[6]; };

__global__ void cvt6(CvtJobs j) {
    const int seg = blockIdx.y;
    const float* s = j.s[seg];
    half_t* d = j.d[seg];
    const int n8 = j.n8[seg];
    for (int i = blockIdx.x*256 + threadIdx.x; i < n8; i += gridDim.x*256) {
        const float4* s4 = (const float4*)s;
        float4 a = s4[2*i], b = s4[2*i+1];
        half8 h;
        h[0]=(_Float16)a.x; h[1]=(_Float16)a.y; h[2]=(_Float16)a.z; h[3]=(_Float16)a.w;
        h[4]=(_Float16)b.x; h[5]=(_Float16)b.y; h[6]=(_Float16)b.z; h[7]=(_Float16)b.w;
        *(half8*)(d + (size_t)i*8) = h;
    }
}

// ---------------- generic NT GEMM: C[m,n] = sum_k A[m,k]*B[n,k] + bias ----------------
// (unchanged from round 10: GATHER=false uses global_load_lds w16, linear dest,
//  source pre-swizzled to preserve the frag-read swizzle; GATHER=true reg-staged.)
template<bool GATHER>
__global__ __launch_bounds__(256)
void gemm_nt(const half_t* __restrict__ A, const float* __restrict__ Atab,
             const int* __restrict__ gidx, const half_t* __restrict__ Bm,
             const float* __restrict__ bias0, const float* __restrict__ bias1,
             half_t* __restrict__ Cout, int M, int N, int K)
{
    __shared__ half8 As8[512];   // 128 x 32 half
    __shared__ half8 Bs8[512];
    half_t* As = (half_t*)As8;
    half_t* Bs = (half_t*)Bs8;

    const int tid  = threadIdx.x;
    const int lane = tid & 63, wid = tid >> 6;
    const int wm = wid >> 1, wn = wid & 1;
    const int ln = lane & 15, hi = lane >> 4;
    const int m0 = blockIdx.x * 128, n0 = blockIdx.y * 128;

    floatx4 acc[4][4] = {};
    const int kTiles = K >> 5;

    const int p0 = tid, p1 = tid + 256;
    const int r0 = p0 >> 2, c0i = ((p0 & 3) - (r0 >> 1)) & 3;
    const int r1 = p1 >> 2, c1i = ((p1 & 3) - (r1 >> 1)) & 3;
    const int wbase0 = (tid & 192);
    const int wbase1 = (tid & 192) + 256;

    const half_t* gA0; const half_t* gA1;
    const half_t* gB0 = Bm + (size_t)(n0 + r0)*K + c0i*8;
    const half_t* gB1 = Bm + (size_t)(n0 + r1)*K + c1i*8;
    half_t* ldsA0 = As + (size_t)wbase0*8;
    half_t* ldsA1 = As + (size_t)wbase1*8;
    half_t* ldsB0 = Bs + (size_t)wbase0*8;
    half_t* ldsB1 = Bs + (size_t)wbase1*8;
    if constexpr (!GATHER) {
        gA0 = A + (size_t)(m0 + r0)*K + c0i*8;
        gA1 = A + (size_t)(m0 + r1)*K + c1i*8;
    }

    for (int kt = 0; kt < kTiles; ++kt) {
        if constexpr (GATHER) {
            {
                int r = tid >> 1, q = tid & 1;
                int row = gidx[m0 + r];
                const float* src = Atab + (size_t)row * EMB + kt*32 + q*16;
                float4 f0 = *(const float4*)(src);
                float4 f1 = *(const float4*)(src + 4);
                float4 f2 = *(const float4*)(src + 8);
                float4 f3 = *(const float4*)(src + 12);
                half8 h0, h1;
                h0[0]=(_Float16)f0.x; h0[1]=(_Float16)f0.y; h0[2]=(_Float16)f0.z; h0[3]=(_Float16)f0.w;
                h0[4]=(_Float16)f1.x; h0[5]=(_Float16)f1.y; h0[6]=(_Float16)f1.z; h0[7]=(_Float16)f1.w;
                h1[0]=(_Float16)f2.x; h1[1]=(_Float16)f2.y; h1[2]=(_Float16)f2.z; h1[3]=(_Float16)f2.w;
                h1[4]=(_Float16)f3.x; h1[5]=(_Float16)f3.y; h1[6]=(_Float16)f3.z; h1[7]=(_Float16)f3.w;
                int c0 = 2*q, c1 = 2*q + 1;
                *(half8*)(As + r*32 + (((c0 + (r>>1)) & 3) * 8)) = h0;
                *(half8*)(As + r*32 + (((c1 + (r>>1)) & 3) * 8)) = h1;
            }
            #pragma unroll
            for (int ii = 0; ii < 2; ++ii) {
                int ch = tid + ii*256; int r = ch >> 2, c = ch & 3;
                half8 v = *(const half8*)(Bm + (size_t)(n0+r)*K + kt*32 + c*8);
                *(half8*)(Bs + r*32 + (((c + (r>>1)) & 3) * 8)) = v;
            }
        } else {
            __builtin_amdgcn_global_load_lds((gv1_t*)gA0, (lv3_t*)ldsA0, 16, 0, 0);
            __builtin_amdgcn_global_load_lds((gv1_t*)gA1, (lv3_t*)ldsA1, 16, 0, 0);
            __builtin_amdgcn_global_load_lds((gv1_t*)gB0, (lv3_t*)ldsB0, 16, 0, 0);
            __builtin_amdgcn_global_load_lds((gv1_t*)gB1, (lv3_t*)ldsB1, 16, 0, 0);
            gA0 += 32; gA1 += 32; gB0 += 32; gB1 += 32;
        }
        __syncthreads();

        half8 af[4], bf[4];
        #pragma unroll
        for (int mt = 0; mt < 4; ++mt) {
            int r = wm*64 + mt*16 + ln;
            af[mt] = *(const half8*)(As + r*32 + ((hi + (r>>1)) & 3) * 8);
        }
        #pragma unroll
        for (int nt = 0; nt < 4; ++nt) {
            int r = wn*64 + nt*16 + ln;
            bf[nt] = *(const half8*)(Bs + r*32 + ((hi + (r>>1)) & 3) * 8);
        }
        #pragma unroll
        for (int mt = 0; mt < 4; ++mt)
            #pragma unroll
            for (int nt = 0; nt < 4; ++nt)
                acc[mt][nt] = __builtin_amdgcn_mfma_f32_16x16x32_f16(af[mt], bf[nt], acc[mt][nt], 0, 0, 0);
        __syncthreads();
    }

    #pragma unroll
    for (int mt = 0; mt < 4; ++mt) {
        #pragma unroll
        for (int nt = 0; nt < 4; ++nt) {
            int n = n0 + wn*64 + nt*16 + ln;
            float bv = (bias0 ? bias0[n] : 0.f) + (bias1 ? bias1[n] : 0.f);
            #pragma unroll
            for (int r = 0; r < 4; ++r) {
                int m = m0 + wm*64 + mt*16 + hi*4 + r;
                Cout[(size_t)m*N + n] = (half_t)(acc[mt][nt][r] + bv);
            }
        }
    }
}

// ---------------- persistent bidirectional RNN layer (round 11) ----------------
// Layout & pipeline = round 9 (verified 464us). Two critical-region moves:
//  (1) global out-stores issue PRE-barrier (barrier is lgkm-only asm; global stores
//      don't touch lgkmcnt -> free). Post-barrier region starts with h reads.
//  (2) W-tail kt=0 reads (STATIC data) pre-issued in the PREVIOUS step's epilogue,
//      held across the barrier (16 regs; cross-barrier live ~242/256). First
//      iteration peeled: wlds isn't published until the prologue barrier.
__global__ __launch_bounds__(512, 2)
void rnn_layer(const half_t* __restrict__ xp, half_t* __restrict__ outbuf,
               const half_t* __restrict__ whh16)
{
    extern __shared__ char smem[];
    char* wlds = smem;                 // [4][512][64B] W k-tail, k-major, full-rank chunk XOR
    char* hlds = smem + WTILE_BYTES;   // [2][16][16][64B] h dbuf, k-major, full-rank chunk XOR

    const int bid = blockIdx.x;
    const int dir = bid >> 2;
    const int bg  = bid & 3;
    const int w   = threadIdx.x >> 6;      // wave 0..7, owns j in [w*64, w*64+64)
    const int lane = threadIdx.x & 63;
    const int ln = lane & 15, hi = lane >> 4;

    const half_t* wbase = whh16 + (size_t)dir * HID * HID;

    // A fragments in regs: afrag[mt][kk] = W[w*64+mt*16+ln][kk*32+hi*8 ..+8], kk<12
    half8 afrag[4][KK_REG];
    #pragma unroll
    for (int mt = 0; mt < 4; ++mt) {
        #pragma unroll
        for (int kk = 0; kk < KK_REG; ++kk)
            afrag[mt][kk] = *(const half8*)(wbase + (size_t)(w*64 + mt*16 + ln)*HID + kk*32 + hi*8);
    }

    // stage W k-tail [384,512) k-major: row j, 16B chunk c8 -> kt=c8>>2, full-rank chunk XOR
    for (int idx = threadIdx.x; idx < HID*16; idx += 512) {
        int row = idx >> 4, c8 = idx & 15;
        int off = ((((c8 & 3) ^ (row & 3) ^ ((row >> 2) & 3)) << 4));
        *(half8*)(wlds + (c8 >> 2)*32768 + row*64 + off) =
            *(const half8*)(wbase + (size_t)row*HID + K_REG + c8*8);
    }

    const int b  = bg*16 + ln;       // this lane's batch column
    const int jq = w*64 + hi*4;      // j quad base; mt adds 16

    const ptrdiff_t dstep = dir ? -(ptrdiff_t)(BATCH*2*HID) : (ptrdiff_t)(BATCH*2*HID);
    const int t0 = dir ? (SEQ-1) : 0;
    const size_t base0 = ((size_t)(t0*BATCH + b))*(2*HID) + (size_t)dir*HID + jq;
    const half_t* xb = xp + base0;
    half_t*       op = outbuf + base0;

    // per-lane LDS bases (full-rank XOR folded; per-access adders bits>=10 -> imm offsets)
    const int swz = ((hi ^ (ln & 3) ^ ((ln >> 2) & 3)) << 4);
    const char* hrdL = hlds + ln*64 + swz;              // + buf*16384 + kk*1024
    const char* wrdL = wlds + (w*64 + ln)*64 + swz;     // + kt*32768 + mt*1024
    char*       hwrL = hlds + (w*2)*1024 + ln*64;       // + buf*16384 + (mt>>1)*1024 + woff
    const int woff0 = ((((hi >> 1) ^ (ln & 3) ^ ((ln >> 2) & 3)) << 4)) + (hi & 1)*8;
    const int woff1 = woff0 ^ 32;

    // ---- step 0: h == 0 -> acc = xq(t0); no h reads, no MFMA ----
    half4 xq[4];
    #pragma unroll
    for (int mt = 0; mt < 4; ++mt) xq[mt] = *(const half4*)(xb + mt*16);
    xb += dstep;

    floatx4 acc[4];
    #pragma unroll
    for (int mt = 0; mt < 4; ++mt) {
        acc[mt][0] = (float)xq[mt][0]; acc[mt][1] = (float)xq[mt][1];
        acc[mt][2] = (float)xq[mt][2]; acc[mt][3] = (float)xq[mt][3];
    }
    // prefetch xq(t1)
    #pragma unroll
    for (int mt = 0; mt < 4; ++mt) xq[mt] = *(const half4*)(xb + mt*16);
    xb += dstep;

    {
        half4 hv[4];
        #pragma unroll
        for (int mt = 0; mt < 4; ++mt) {
            #pragma unroll
            for (int r = 0; r < 4; ++r)
                hv[mt][r] = (_Float16)fmaxf(acc[mt][r], 0.f);
            *(half4*)(hwrL + (mt >> 1)*1024 + ((mt & 1) ? woff1 : woff0)) = hv[mt];  // buf 0
            *(half4*)(op + mt*16) = hv[mt];
        }
        op += dstep;
    }
    // pre-barrier seed for step 1 (xq = xp(t1)); issue xq(t2) loads
    #pragma unroll
    for (int mt = 0; mt < 4; ++mt) {
        acc[mt][0] = (float)xq[mt][0]; acc[mt][1] = (float)xq[mt][1];
        acc[mt][2] = (float)xq[mt][2]; acc[mt][3] = (float)xq[mt][3];
    }
    #pragma unroll
    for (int mt = 0; mt < 4; ++mt) xq[mt] = *(const half4*)(xb + mt*16);
    xb += dstep;
    // publish wlds staging + step-0 h writes
    asm volatile("s_waitcnt lgkmcnt(0)\n\ts_barrier" ::: "memory");

    // peel: first load of the static W-tail kt=0 group (wlds now published)
    half8 wA0 = *(const half8*)(wrdL + 0*32768 + 0*1024);
    half8 wA1 = *(const half8*)(wrdL + 0*32768 + 1*1024);
    half8 wA2 = *(const half8*)(wrdL + 0*32768 + 2*1024);
    half8 wA3 = *(const half8*)(wrdL + 0*32768 + 3*1024);
    half8 wB0, wB1, wB2, wB3, chA, chB;

    for (int step = 1; step < SEQ; ++step) {
        const int rb = (step + 1) & 1;   // buffer holding h from previous step
        const int wb = step & 1;         // buffer to write h of this step
        const char* hrd = hrdL + rb*HBUF_BYTES;

        // acc seeded + wA(kt=0) resident from before the barrier
        __builtin_amdgcn_s_setprio(1);
        // ---- k < 384: W in regs, h from LDS (2-deep paired pipeline, imm offsets) ----
        half8 c0 = *(const half8*)(hrd + 0*1024);
        half8 c1 = *(const half8*)(hrd + 1*1024);
        #pragma unroll
        for (int g = 0; g < 5; ++g) {
            half8 n0 = *(const half8*)(hrd + (2*g+2)*1024);
            half8 n1 = *(const half8*)(hrd + (2*g+3)*1024);
            #pragma unroll
            for (int mt = 0; mt < 4; ++mt)
                acc[mt] = __builtin_amdgcn_mfma_f32_16x16x32_f16(afrag[mt][2*g],   c0, acc[mt], 0, 0, 0);
            #pragma unroll
            for (int mt = 0; mt < 4; ++mt)
                acc[mt] = __builtin_amdgcn_mfma_f32_16x16x32_f16(afrag[mt][2*g+1], c1, acc[mt], 0, 0, 0);
            c0 = n0; c1 = n1;
        }
        // h-tail ch(kt=0) read in the shadow of the kk=10/11 MFMAs (wA already resident)
        chA = *(const half8*)(hrd + 12*1024);
        #pragma unroll
        for (int mt = 0; mt < 4; ++mt)
            acc[mt] = __builtin_amdgcn_mfma_f32_16x16x32_f16(afrag[mt][10], c0, acc[mt], 0, 0, 0);
        #pragma unroll
        for (int mt = 0; mt < 4; ++mt)
            acc[mt] = __builtin_amdgcn_mfma_f32_16x16x32_f16(afrag[mt][11], c1, acc[mt], 0, 0, 0);

        // ---- k in [384,512): hand-pipelined 2-deep, rotating A/B name sets ----
        chB = *(const half8*)(hrd + 13*1024);
        wB0 = *(const half8*)(wrdL + 1*32768 + 0*1024);
        wB1 = *(const half8*)(wrdL + 1*32768 + 1*1024);
        acc[0] = __builtin_amdgcn_mfma_f32_16x16x32_f16(wA0, chA, acc[0], 0, 0, 0);
        acc[1] = __builtin_amdgcn_mfma_f32_16x16x32_f16(wA1, chA, acc[1], 0, 0, 0);
        wB2 = *(const half8*)(wrdL + 1*32768 + 2*1024);
        wB3 = *(const half8*)(wrdL + 1*32768 + 3*1024);
        acc[2] = __builtin_amdgcn_mfma_f32_16x16x32_f16(wA2, chA, acc[2], 0, 0, 0);
        acc[3] = __builtin_amdgcn_mfma_f32_16x16x32_f16(wA3, chA, acc[3], 0, 0, 0);
        chA = *(const half8*)(hrd + 14*1024);
        wA0 = *(const half8*)(wrdL + 2*32768 + 0*1024);
        wA1 = *(const half8*)(wrdL + 2*32768 + 1*1024);
        acc[0] = __builtin_amdgcn_mfma_f32_16x16x32_f16(wB0, chB, acc[0], 0, 0, 0);
        acc[1] = __builtin_amdgcn_mfma_f32_16x16x32_f16(wB1, chB, acc[1], 0, 0, 0);
        wA2 = *(const half8*)(wrdL + 2*32768 + 2*1024);
        wA3 = *(const half8*)(wrdL + 2*32768 + 3*1024);
        acc[2] = __builtin_amdgcn_mfma_f32_16x16x32_f16(wB2, chB, acc[2], 0, 0, 0);
        acc[3] = __builtin_amdgcn_mfma_f32_16x16x32_f16(wB3, chB, acc[3], 0, 0, 0);
        chB = *(const half8*)(hrd + 15*1024);
        wB0 = *(const half8*)(wrdL + 3*32768 + 0*1024);
        wB1 = *(const half8*)(wrdL + 3*32768 + 1*1024);
        acc[0] = __builtin_amdgcn_mfma_f32_16x16x32_f16(wA0, chA, acc[0], 0, 0, 0);
        acc[1] = __builtin_amdgcn_mfma_f32_16x16x32_f16(wA1, chA, acc[1], 0, 0, 0);
        wB2 = *(const half8*)(wrdL + 3*32768 + 2*1024);
        wB3 = *(const half8*)(wrdL + 3*32768 + 3*1024);
        acc[2] = __builtin_amdgcn_mfma_f32_16x16x32_f16(wA2, chA, acc[2], 0, 0, 0);
        acc[3] = __builtin_amdgcn_mfma_f32_16x16x32_f16(wA3, chA, acc[3], 0, 0, 0);
        acc[0] = __builtin_amdgcn_mfma_f32_16x16x32_f16(wB0, chB, acc[0], 0, 0, 0);
        acc[1] = __builtin_amdgcn_mfma_f32_16x16x32_f16(wB1, chB, acc[1], 0, 0, 0);
        acc[2] = __builtin_amdgcn_mfma_f32_16x16x32_f16(wB2, chB, acc[2], 0, 0, 0);
        acc[3] = __builtin_amdgcn_mfma_f32_16x16x32_f16(wB3, chB, acc[3], 0, 0, 0);
        __builtin_amdgcn_s_setprio(0);

        // ---- epilogue: hv = relu(acc) ----
        half4 hv[4];
        #pragma unroll
        for (int mt = 0; mt < 4; ++mt) {
            #pragma unroll
            for (int r = 0; r < 4; ++r)
                hv[mt][r] = (_Float16)fmaxf(acc[mt][r], 0.f);
        }

        if (step + 1 < SEQ) {
            char* hw = hwrL + wb*HBUF_BYTES;
            #pragma unroll
            for (int mt = 0; mt < 4; ++mt)
                *(half4*)(hw + (mt >> 1)*1024 + ((mt & 1) ? woff1 : woff0)) = hv[mt];
            // global out-stores PRE-barrier (lgkm-only barrier -> free; clears the
            // post-barrier issue window)
            #pragma unroll
            for (int mt = 0; mt < 4; ++mt)
                *(half4*)(op + mt*16) = hv[mt];
            op += dstep;
            // pre-issue next step's static W-tail kt=0 reads (held across barrier)
            wA0 = *(const half8*)(wrdL + 0*32768 + 0*1024);
            wA1 = *(const half8*)(wrdL + 0*32768 + 1*1024);
            wA2 = *(const half8*)(wrdL + 0*32768 + 2*1024);
            wA3 = *(const half8*)(wrdL + 0*32768 + 3*1024);
            // pre-barrier: seed acc for step+1; issue xq(t(step+2))
            #pragma unroll
            for (int mt = 0; mt < 4; ++mt) {
                acc[mt][0] = (float)xq[mt][0]; acc[mt][1] = (float)xq[mt][1];
                acc[mt][2] = (float)xq[mt][2]; acc[mt][3] = (float)xq[mt][3];
            }
            if (step + 2 < SEQ) {
                #pragma unroll
                for (int mt = 0; mt < 4; ++mt) xq[mt] = *(const half4*)(xb + mt*16);
            }
            xb += dstep;
            // single barrier: publishes h(t+1) AND proves all reads of rb finished
            asm volatile("s_waitcnt lgkmcnt(0)\n\ts_barrier" ::: "memory");
        } else {
            #pragma unroll
            for (int mt = 0; mt < 4; ++mt)
                *(half4*)(op + mt*16) = hv[mt];
            op += dstep;
        }
    }
}

// ---------------- final FC: [16384,1024] x [18,1024]^T + b ----------------
__global__ __launch_bounds__(256)
void fc_kernel(const half_t* __restrict__ X, const half_t* __restrict__ W16,
               const float* __restrict__ bias, float* __restrict__ Y)
{
    __shared__ half8 Ws8[2304];   // 18*1024 half
    half_t* Ws = (half_t*)Ws8;
    for (int ch = threadIdx.x; ch < 2304; ch += 256)
        Ws8[ch] = *(const half8*)(W16 + (size_t)ch*8);
    __syncthreads();

    int wi = threadIdx.x >> 6, lane = threadIdx.x & 63;
    int m = blockIdx.x*4 + wi;
    const half_t* xr = X + (size_t)m*1024 + lane*16;
    half8 x0 = *(const half8*)xr;
    half8 x1 = *(const half8*)(xr + 8);
    float xa[16];
    #pragma unroll
    for (int i = 0; i < 8; ++i) { xa[i] = (float)x0[i]; xa[8+i] = (float)x1[i]; }

    for (int n = 0; n < NOUT; ++n) {
        const half_t* wr = Ws + n*1024 + lane*16;
        half8 w0 = *(const half8*)wr;
        half8 w1 = *(const half8*)(wr + 8);
        float s = 0.f;
        #pragma unroll
        for (int i = 0; i < 8; ++i) s += xa[i]*(float)w0[i] + xa[8+i]*(float)w1[i];
        #pragma unroll
        for (int off = 32; off > 0; off >>= 1) s += __shfl_down(s, off, 64);
        if (lane == 0) Y[(size_t)m*NOUT + n] = s + bias[n];
    }
}

// ---------------- launcher ----------------
extern "C" void kernel_launch(void* const* d_in, const int* in_sizes, int n_in,
                              void* d_out, int out_size, void* d_ws, size_t ws_size,
                              hipStream_t stream)
{
    const int*   text    = (const int*)  d_in[0];
    const float* emb     = (const float*)d_in[1];
    const float* emfc_w  = (const float*)d_in[2];
    const float* emfc_b  = (const float*)d_in[3];
    const float* w_ih0   = (const float*)d_in[4];
    const float* w_hh0   = (const float*)d_in[5];
    const float* b_ih0   = (const float*)d_in[6];
    const float* b_hh0   = (const float*)d_in[7];
    const float* w_ih1   = (const float*)d_in[8];
    const float* w_hh1   = (const float*)d_in[9];
    const float* b_ih1   = (const float*)d_in[10];
    const float* b_hh1   = (const float*)d_in[11];
    const float* fc_w    = (const float*)d_in[12];
    const float* fc_b    = (const float*)d_in[13];
    float* out = (float*)d_out;

    char* ws = (char*)d_ws;
    half_t* whh0_16 = (half_t*)(ws + O_WHH0_16);
    half_t* whh1_16 = (half_t*)(ws + O_WHH1_16);
    half_t* emfc16  = (half_t*)(ws + O_EMFC16);
    half_t* wih0    = (half_t*)(ws + O_WIH0);
    half_t* wih1    = (half_t*)(ws + O_WIH1);
    half_t* fc16    = (half_t*)(ws + O_FC16);
    half_t* pe      = (half_t*)(ws + O_PE);
    half_t* xp      = (half_t*)(ws + O_XP);
    half_t* out0    = (half_t*)(ws + O_OUT);
    half_t* out1    = (half_t*)(ws + O_OUT);   // aliased: out0 dead once xp1 GEMM done

    // one-time: allow full 160KB dynamic LDS for rnn_layer (host-side attr; capture-safe)
    static int attr_done = 0;
    if (!attr_done) {
        hipFuncSetAttribute((const void*)rnn_layer,
                            hipFuncAttributeMaxDynamicSharedMemorySize, LDS_BYTES);
        attr_done = 1;
    }

    // 1) weight conversions fp32->fp16 (fused, single launch)
    CvtJobs jobs;
    jobs.s[0] = emfc_w; jobs.d[0] = emfc16;  jobs.n8[0] = 8192;
    jobs.s[1] = w_ih0;  jobs.d[1] = wih0;    jobs.n8[1] = 32768;
    jobs.s[2] = w_ih1;  jobs.d[2] = wih1;    jobs.n8[2] = 131072;
    jobs.s[3] = w_hh0;  jobs.d[3] = whh0_16; jobs.n8[3] = 65536;
    jobs.s[4] = w_hh1;  jobs.d[4] = whh1_16; jobs.n8[4] = 65536;
    jobs.s[5] = fc_w;   jobs.d[5] = fc16;    jobs.n8[5] = 2304;
    cvt6<<<dim3(128, 6), 256, 0, stream>>>(jobs);

    // 2) post_emb = gather(emb, text) @ emfc_w^T + emfc_b
    gemm_nt<true><<<dim3(M_TOT/128, EMB/128), 256, 0, stream>>>(
        nullptr, emb, text, emfc16, emfc_b, nullptr, pe, M_TOT, EMB, EMB);

    // 3) xp0 = post_emb @ w_ih0^T + (b_ih0 + b_hh0)
    gemm_nt<false><<<dim3(M_TOT/128, (2*HID)/128), 256, 0, stream>>>(
        pe, nullptr, nullptr, wih0, b_ih0, b_hh0, xp, M_TOT, 2*HID, EMB);

    // 4) layer0 recurrence (8 independent blocks x 8 waves)
    rnn_layer<<<8, 512, LDS_BYTES, stream>>>(xp, out0, whh0_16);

    // 5) xp1 = out0 @ w_ih1^T + (b_ih1 + b_hh1)
    gemm_nt<false><<<dim3(M_TOT/128, (2*HID)/128), 256, 0, stream>>>(
        out0, nullptr, nullptr, wih1, b_ih1, b_hh1, xp, M_TOT, 2*HID, 2*HID);

    // 6) layer1 recurrence
    rnn_layer<<<8, 512, LDS_BYTES, stream>>>(xp, out1, whh1_16);

    // 7) out = out1 @ fc_w^T + fc_b
    fc_kernel<<<M_TOT/4, 256, 0, stream>>>(out1, fc16, fc_b, out);
}